// Round 13
// baseline (189.984 us; speedup 1.0000x reference)
//
#include <hip/hip_runtime.h>
#include <float.h>

#define N_PTS 6144
#define D_IN  512
#define H1_DIM 256
#define H2_DIM 128
#define G_DIM  64
#define KNN    32
#define NOUT   22

typedef short s8v __attribute__((ext_vector_type(8)));   // 8 bf16 in 4 VGPR
typedef float f32x4 __attribute__((ext_vector_type(4)));
typedef unsigned u32x4 __attribute__((ext_vector_type(4)));
typedef unsigned short u16;
typedef unsigned long long u64;

__device__ __forceinline__ u16 f2bf(float f) {
  unsigned u = __float_as_uint(f);
  u += 0x7FFFu + ((u >> 16) & 1u);          // RNE to bf16
  return (u16)(u >> 16);
}
__device__ __forceinline__ float bf2f(u16 s) {
  return __uint_as_float(((unsigned)s) << 16);
}
__device__ __forceinline__ void split3(float v, u16& a0, u16& a1, u16& a2) {
  a0 = f2bf(v);
  float r1 = v - bf2f(a0);
  a1 = f2bf(r1);
  a2 = f2bf(r1 - bf2f(a1));
}

// ---------------------------------------------------------------------------
// MFMA GEMM, 3-way bf16 split, 6-term schedule (fp32-equivalent).
// C[M,N] = A[M,K] * B^T[N,K].  BN=64, BK=32, 4 waves (2x2), wave tile (BM/2)x32.
// WKEY: epilogue writes sortable-u32 kNN keys (sq[col] - 2*val; diag=UINT_MAX).
// ---------------------------------------------------------------------------
template<int BM, bool AF32, bool SPLITK, bool BIAS, bool RELU, bool WF32, bool WSPLIT, bool WKEY>
__global__ __launch_bounds__(256, 4) void mfma_gemm(
    const void* __restrict__ A0any, const u16* __restrict__ A1_, const u16* __restrict__ A2_,
    const u16* __restrict__ B0_, const u16* __restrict__ B1_, const u16* __restrict__ B2_,
    const float* __restrict__ bias,
    float* __restrict__ Cf, u16* __restrict__ C0, u16* __restrict__ C1, u16* __restrict__ C2,
    int Ktot, int Ks, int ldC, size_t MN, int rowoff)
{
  const int MT = BM / 32, NT = 2;
  __shared__ u16 lds[(BM + 64) * 32 * 3];
  u16* Ap[3] = { lds, lds + BM * 32, lds + 2 * BM * 32 };
  u16* Bp[3] = { lds + 3 * BM * 32, lds + 3 * BM * 32 + 2048, lds + 3 * BM * 32 + 4096 };

  const int t = threadIdx.x;
  const int lane = t & 63, wave = t >> 6;
  const int wm = wave >> 1, wn = wave & 1;
  const int m0 = blockIdx.y * BM, n0 = blockIdx.x * 64;
  const int kz = blockIdx.z * Ks;

  f32x4 acc[MT][NT] = {};

  for (int k0 = 0; k0 < Ks; k0 += 32) {
    if (k0) __syncthreads();
    const int kb = kz + k0;
    if (AF32) {
      const float* A = (const float*)A0any;
      #pragma unroll
      for (int c0 = 0; c0 < BM * 4; c0 += 256) {
        int c = c0 + t;
        int row = c >> 2, slot = c & 3;
        const float* g = A + (size_t)(m0 + row) * Ktot + kb + slot * 8;
        f32x4 fa = *(const f32x4*)g;
        f32x4 fb = *(const f32x4*)(g + 4);
        int dst = row * 32 + ((slot ^ ((row >> 1) & 3)) << 3);
        s8v v0, v1, v2;
        #pragma unroll
        for (int e = 0; e < 4; ++e) {
          u16 a0, a1, a2; split3(fa[e], a0, a1, a2);
          v0[e] = (short)a0; v1[e] = (short)a1; v2[e] = (short)a2;
        }
        #pragma unroll
        for (int e = 0; e < 4; ++e) {
          u16 a0, a1, a2; split3(fb[e], a0, a1, a2);
          v0[4 + e] = (short)a0; v1[4 + e] = (short)a1; v2[4 + e] = (short)a2;
        }
        *(s8v*)(Ap[0] + dst) = v0;
        *(s8v*)(Ap[1] + dst) = v1;
        *(s8v*)(Ap[2] + dst) = v2;
      }
    } else {
      const u16* As[3] = { (const u16*)A0any, A1_, A2_ };
      #pragma unroll
      for (int c0 = 0; c0 < BM * 4; c0 += 256) {
        int c = c0 + t;
        int row = c >> 2, slot = c & 3;
        size_t g = (size_t)(m0 + row) * Ktot + kb + slot * 8;
        int dst = row * 32 + ((slot ^ ((row >> 1) & 3)) << 3);
        #pragma unroll
        for (int p = 0; p < 3; ++p)
          *(s8v*)(Ap[p] + dst) = *(const s8v*)(As[p] + g);
      }
    }
    {
      const u16* Bs[3] = { B0_, B1_, B2_ };
      int row = t >> 2, slot = t & 3;
      size_t g = (size_t)(n0 + row) * Ktot + kb + slot * 8;
      int dst = row * 32 + ((slot ^ ((row >> 1) & 3)) << 3);
      #pragma unroll
      for (int p = 0; p < 3; ++p)
        *(s8v*)(Bp[p] + dst) = *(const s8v*)(Bs[p] + g);
    }
    __syncthreads();

    s8v af[3][MT], bf[3][NT];
    #pragma unroll
    for (int mt = 0; mt < MT; ++mt) {
      int r = wm * (BM / 2) + mt * 16 + (lane & 15);
      int off = r * 32 + (((lane >> 4) ^ ((r >> 1) & 3)) << 3);
      #pragma unroll
      for (int p = 0; p < 3; ++p) af[p][mt] = *(const s8v*)(Ap[p] + off);
    }
    #pragma unroll
    for (int nt = 0; nt < NT; ++nt) {
      int r = wn * 32 + nt * 16 + (lane & 15);
      int off = r * 32 + (((lane >> 4) ^ ((r >> 1) & 3)) << 3);
      #pragma unroll
      for (int p = 0; p < 3; ++p) bf[p][nt] = *(const s8v*)(Bp[p] + off);
    }
    #pragma unroll
    for (int mt = 0; mt < MT; ++mt)
      #pragma unroll
      for (int nt = 0; nt < NT; ++nt) {
        f32x4 a = acc[mt][nt];
        a = __builtin_amdgcn_mfma_f32_16x16x32_bf16(af[0][mt], bf[0][nt], a, 0, 0, 0);
        a = __builtin_amdgcn_mfma_f32_16x16x32_bf16(af[0][mt], bf[1][nt], a, 0, 0, 0);
        a = __builtin_amdgcn_mfma_f32_16x16x32_bf16(af[1][mt], bf[0][nt], a, 0, 0, 0);
        a = __builtin_amdgcn_mfma_f32_16x16x32_bf16(af[1][mt], bf[1][nt], a, 0, 0, 0);
        a = __builtin_amdgcn_mfma_f32_16x16x32_bf16(af[0][mt], bf[2][nt], a, 0, 0, 0);
        a = __builtin_amdgcn_mfma_f32_16x16x32_bf16(af[2][mt], bf[0][nt], a, 0, 0, 0);
        acc[mt][nt] = a;
      }
  }

  #pragma unroll
  for (int mt = 0; mt < MT; ++mt) {
    #pragma unroll
    for (int nt = 0; nt < NT; ++nt) {
      int col = n0 + wn * 32 + nt * 16 + (lane & 15);
      float bv = (BIAS && !SPLITK) ? bias[col] : 0.f;
      float sqc = WKEY ? bias[col] : 0.f;
      #pragma unroll
      for (int v = 0; v < 4; ++v) {
        int row = m0 + wm * (BM / 2) + mt * 16 + (lane >> 4) * 4 + v;
        float val = acc[mt][nt][v] + bv;
        size_t o = (size_t)row * ldC + col;
        if (SPLITK) {
          Cf[(size_t)blockIdx.z * MN + o] = val;
        } else if (WKEY) {
          float f = fmaf(-2.f, val, sqc);
          unsigned ub = __float_as_uint(f);
          unsigned uu = (ub & 0x80000000u) ? ~ub : (ub | 0x80000000u);
          if (rowoff + row == col) uu = 0xFFFFFFFFu;
          ((unsigned*)Cf)[o] = uu;
        } else {
          if (RELU) val = fmaxf(val, 0.f);
          if (WF32) Cf[o] = val;
          if (WSPLIT) {
            u16 a0, a1, a2; split3(val, a0, a1, a2);
            C0[o] = a0; C1[o] = a1; C2[o] = a2;
          }
        }
      }
    }
  }
}

template<int S, bool BIAS, bool RELU, bool WF32, bool WSPLIT>
__global__ void combine(const float* __restrict__ P, const float* __restrict__ bias,
                        size_t MN, int Ncols,
                        float* __restrict__ Cf, u16* __restrict__ C0,
                        u16* __restrict__ C1, u16* __restrict__ C2)
{
  size_t idx = ((size_t)blockIdx.x * 256 + threadIdx.x) * 4;
  if (idx >= MN) return;
  f32x4 s = *(const f32x4*)(P + idx);
  #pragma unroll
  for (int z = 1; z < S; ++z) s += *(const f32x4*)(P + (size_t)z * MN + idx);
  int n = (int)(idx % (size_t)Ncols);
  #pragma unroll
  for (int e = 0; e < 4; ++e) {
    float v = s[e] + (BIAS ? bias[n + e] : 0.f);
    if (RELU) v = fmaxf(v, 0.f);
    if (WF32) Cf[idx + e] = v;
    if (WSPLIT) {
      u16 a0, a1, a2; split3(v, a0, a1, a2);
      C0[idx + e] = a0; C1[idx + e] = a1; C2[idx + e] = a2;
    }
  }
}

// all three weight transposes+splits in one launch
__global__ void trans_split3(const float* __restrict__ W0, u16* __restrict__ a0,
                             u16* __restrict__ a1, u16* __restrict__ a2,
                             const float* __restrict__ W1, u16* __restrict__ b0,
                             u16* __restrict__ b1, u16* __restrict__ b2,
                             const float* __restrict__ gW, u16* __restrict__ c0,
                             u16* __restrict__ c1, u16* __restrict__ c2)
{
  int id = blockIdx.x * 256 + threadIdx.x;
  const int S0 = D_IN * H1_DIM, S1 = H1_DIM * H2_DIM, S2 = H2_DIM * G_DIM;
  const float* W; u16 *p0, *p1, *p2; int K, N;
  if (id < S0)           { W = W0; p0 = a0; p1 = a1; p2 = a2; K = D_IN;   N = H1_DIM; }
  else if (id < S0 + S1) { id -= S0; W = W1; p0 = b0; p1 = b1; p2 = b2; K = H1_DIM; N = H2_DIM; }
  else if (id < S0 + S1 + S2) { id -= S0 + S1; W = gW; p0 = c0; p1 = c1; p2 = c2; K = H2_DIM; N = G_DIM; }
  else return;
  int k = id / N, n = id % N;
  u16 x0, x1, x2;
  split3(W[id], x0, x1, x2);
  size_t o = (size_t)n * K + k;
  p0[o] = x0; p1[o] = x1; p2[o] = x2;
}

__global__ void prep_head(const float* __restrict__ cW, const float* __restrict__ cb,
                          const float* __restrict__ dW, const float* __restrict__ db,
                          float* __restrict__ Wc, float* __restrict__ bc)
{
  int t = threadIdx.x;
  for (int idx = t; idx < 64 * NOUT; idx += 256) {
    int g = idx / NOUT, c = idx % NOUT;
    float s = 0.f;
    if (c < 16) {
      for (int r = 0; r < 8; ++r) s += cW[(r * 64 + g) * 16 + c];
    } else {
      int k = (c - 16) >> 1, o = (c - 16) & 1;
      for (int r = 0; r < 8; ++r) s += dW[k * 1024 + (r * 64 + g) * 2 + o];
    }
    Wc[idx] = s;
  }
  if (t < NOUT) bc[t] = (t < 16) ? cb[t] : db[t - 16];
}

__global__ void row_stats(const float* __restrict__ h, const float* __restrict__ Wh,
                          const float* __restrict__ ga, float* __restrict__ sq,
                          float* __restrict__ f1, float* __restrict__ f2)
{
  int i = blockIdx.x * 256 + threadIdx.x;
  const float* hr = h + (size_t)i * H2_DIM;
  float s = 0.f;
  for (int k = 0; k < H2_DIM; ++k) { float v = hr[k]; s = fmaf(v, v, s); }
  sq[i] = s;
  const float* wr = Wh + (size_t)i * G_DIM;
  float a = 0.f, b = 0.f;
  for (int g = 0; g < G_DIM; ++g) {
    float w = wr[g];
    a = fmaf(w, ga[g], a);
    b = fmaf(w, ga[G_DIM + g], b);
  }
  f1[i] = a; f2[i] = b;
}

// ---------------------------------------------------------------------------
// ONE WAVE PER ROW. Selection threshold from order statistics: sort the 64
// per-lane quad-mins (register bitonic), Q = s[31]. Guarantee: >=32 lanes
// have lane-min <= s[31], each contributes >=1 key <= s[31] => exact
// threshold T <= Q, so every winner's quad qualifies. If >64 quads qualify
// (rare), refine Q with the exact quaternary bisection and re-collect.
// Then ballot-prefix collection + bitonic sort on (key<<13|j) -> exact
// top-32 with np tie-break; wave-local softmax + PV + head.
// ---------------------------------------------------------------------------
__global__ __launch_bounds__(256) void topk_att(const unsigned* __restrict__ Sb,
    const float* __restrict__ f1, const float* __restrict__ f2,
    const float* __restrict__ Wh, const float* __restrict__ Wc, const float* __restrict__ bc,
    float* __restrict__ out, int m0)
{
  const int t = threadIdx.x;
  const int lane = t & 63, wv = t >> 6;
  const int row4 = blockIdx.x * 4 + wv;
  const int i = m0 + row4;
  const unsigned* Srow = Sb + (size_t)row4 * N_PTS;

  __shared__ float WcL[64 * NOUT];
  __shared__ u64 candS[4][256];
  __shared__ int neighS[4][33];
  __shared__ float attS[4][33];
  __shared__ float hpfS[4][64];

  for (int idx = t; idx < 64 * NOUT; idx += 256) WcL[idx] = Wc[idx];
  __syncthreads();                       // only block barrier

  // ---- stream row, keep quad-mins: j = (c<<8) + (lane<<2) + e ----
  unsigned q[24];
  #pragma unroll
  for (int c = 0; c < 24; ++c) {
    u32x4 v = *(const u32x4*)(Srow + (c << 8) + (lane << 2));
    unsigned a = v[0] < v[1] ? v[0] : v[1];
    unsigned b = v[2] < v[3] ? v[2] : v[3];
    q[c] = a < b ? a : b;
  }

  // lane-min of the 24 quads
  unsigned lmin = q[0];
  #pragma unroll
  for (int c = 1; c < 24; ++c) lmin = q[c] < lmin ? q[c] : lmin;

  // register bitonic sort of the 64 lane-mins (ascending across lanes)
  unsigned sv = lmin;
  for (int k = 2; k <= 64; k <<= 1) {
    for (int j = k >> 1; j >= 1; j >>= 1) {
      unsigned o = __shfl_xor(sv, j);
      bool up = ((lane & k) == 0) == ((lane & j) == 0);
      sv = up ? (sv < o ? sv : o) : (sv > o ? sv : o);
    }
  }
  unsigned Q = __shfl(sv, 31);          // 32nd-smallest lane-min
  const unsigned s0 = __shfl(sv, 0);    // wave min (for fallback interval)

  const u64 below = (lane == 0) ? 0ull : (~0ull >> (64 - lane));

  // ---- collection with capacity 64 (init all 256 slots) ----
  candS[wv][lane] = ~0ull;
  candS[wv][64 + lane] = ~0ull;
  candS[wv][128 + lane] = ~0ull;
  candS[wv][192 + lane] = ~0ull;
  int cnt = 0;
  #pragma unroll
  for (int c = 0; c < 24; ++c) {
    bool act = (q[c] <= Q);
    u64 mask = __ballot(act);
    if (act) {
      int pos = cnt + (int)__popcll(mask & below);
      if (pos < 64) {
        u32x4 v = *(const u32x4*)(Srow + (c << 8) + (lane << 2));
        #pragma unroll
        for (int e = 0; e < 4; ++e) {
          int j = (c << 8) + (lane << 2) + e;
          candS[wv][pos * 4 + e] = ((u64)v[e] << 13) | (unsigned)j;
        }
      }
    }
    cnt += (int)__popcll(mask);
  }

  if (cnt > 64) {
    // rare: refine to exact 32nd-smallest quad-min by quaternary bisection
    long long lo = (long long)s0 - 1, hi = (long long)Q;
    while (hi - lo > 1) {
      long long span = hi - lo;
      unsigned m1 = (unsigned)(lo + (span >> 2));
      unsigned m2 = (unsigned)(lo + (span >> 1));
      unsigned m3 = (unsigned)(hi - (span >> 2));
      int c1 = 0, c2 = 0, c3 = 0;
      #pragma unroll
      for (int c = 0; c < 24; ++c) {
        c1 += (q[c] <= m1);
        c2 += (q[c] <= m2);
        c3 += (q[c] <= m3);
      }
      #pragma unroll
      for (int off = 32; off > 0; off >>= 1) {
        c1 += __shfl_xor(c1, off);
        c2 += __shfl_xor(c2, off);
        c3 += __shfl_xor(c3, off);
      }
      if (c1 >= KNN)       { hi = m1; }
      else if (c2 >= KNN)  { lo = m1; hi = m2; }
      else if (c3 >= KNN)  { lo = m2; hi = m3; }
      else                 { lo = m3; }
    }
    Q = (unsigned)hi;
    candS[wv][lane] = ~0ull;
    candS[wv][64 + lane] = ~0ull;
    candS[wv][128 + lane] = ~0ull;
    candS[wv][192 + lane] = ~0ull;
    cnt = 0;
    #pragma unroll
    for (int c = 0; c < 24; ++c) {
      bool act = (q[c] <= Q);
      u64 mask = __ballot(act);
      if (act) {
        int pos = cnt + (int)__popcll(mask & below);
        if (pos < 64) {
          u32x4 v = *(const u32x4*)(Srow + (c << 8) + (lane << 2));
          #pragma unroll
          for (int e = 0; e < 4; ++e) {
            int j = (c << 8) + (lane << 2) + e;
            candS[wv][pos * 4 + e] = ((u64)v[e] << 13) | (unsigned)j;
          }
        }
      }
      cnt += (int)__popcll(mask);
    }
  }

  if (cnt <= 32) {
    // ---- register bitonic sort of 128 candidates, 2 elems/lane ----
    u64 v0 = candS[wv][2 * lane], v1 = candS[wv][2 * lane + 1];
    const int e0 = 2 * lane, e1 = e0 + 1;
    for (int k = 2; k <= 128; k <<= 1) {
      for (int j = k >> 1; j >= 2; j >>= 1) {
        int half = j >> 1;
        u64 o0 = __shfl_xor(v0, half);
        u64 o1 = __shfl_xor(v1, half);
        bool up0 = ((e0 & k) == 0) == ((e0 & j) == 0);
        bool up1 = ((e1 & k) == 0) == ((e1 & j) == 0);
        v0 = up0 ? (v0 < o0 ? v0 : o0) : (v0 > o0 ? v0 : o0);
        v1 = up1 ? (v1 < o1 ? v1 : o1) : (v1 > o1 ? v1 : o1);
      }
      bool asc = ((e0 & k) == 0);
      u64 a = v0 < v1 ? v0 : v1, b = v0 < v1 ? v1 : v0;
      v0 = asc ? a : b;
      v1 = asc ? b : a;
    }
    if (lane < 16) {
      neighS[wv][2 * lane]     = (int)(v0 & 0x1FFFu);
      neighS[wv][2 * lane + 1] = (int)(v1 & 0x1FFFu);
    }
    if (lane == 0) neighS[wv][32] = i;
  } else {
    // in-LDS 256-elem bitonic (up to 64 quads)
    for (int k = 2; k <= 256; k <<= 1) {
      for (int j = k >> 1; j >= 1; j >>= 1) {
        #pragma unroll
        for (int s = 0; s < 4; ++s) {
          int e = lane + s * 64;
          int p = e ^ j;
          if (p > e) {
            u64 a = candS[wv][e], b = candS[wv][p];
            bool asc = ((e & k) == 0);
            if ((a > b) == asc) { candS[wv][e] = b; candS[wv][p] = a; }
          }
        }
      }
    }
    if (lane < KNN) neighS[wv][lane] = (int)(candS[wv][lane] & 0x1FFFu);
    if (lane == 0) neighS[wv][32] = i;
  }

  // ---- wave-local masked softmax over 33 entries ----
  {
    float e = -FLT_MAX;
    if (lane < 33) {
      float raw = f1[i] + f2[neighS[wv][lane]];
      e = raw > 0.f ? raw : 0.2f * raw;
    }
    float mx = e;
    #pragma unroll
    for (int off = 32; off > 0; off >>= 1) mx = fmaxf(mx, __shfl_xor(mx, off));
    float ex = (lane < 33) ? expf(e - mx) : 0.f;
    float sm = ex;
    #pragma unroll
    for (int off = 32; off > 0; off >>= 1) sm += __shfl_xor(sm, off);
    if (lane < 33) attS[wv][lane] = ex / sm;
  }

  // ---- PV: lane = g; hp[g] = sum_m att[m] * Wh[neigh[m]][g]; elu ----
  {
    float s = 0.f;
    for (int m = 0; m < 33; ++m)
      s = fmaf(attS[wv][m], Wh[(size_t)neighS[wv][m] * G_DIM + lane], s);
    hpfS[wv][lane] = s > 0.f ? s : expm1f(s);
  }

  // ---- head: 64 -> 22 ----
  if (lane < NOUT) {
    float o = bc[lane];
    for (int g = 0; g < 64; ++g) o = fmaf(hpfS[wv][g], WcL[g * NOUT + lane], o);
    out[(size_t)i * NOUT + lane] = o;
  }
}

extern "C" void kernel_launch(void* const* d_in, const int* in_sizes, int n_in,
                              void* d_out, int out_size, void* d_ws, size_t ws_size,
                              hipStream_t stream)
{
  const float* x  = (const float*)d_in[0];
  const float* W0 = (const float*)d_in[1];
  const float* b0 = (const float*)d_in[2];
  const float* W1 = (const float*)d_in[3];
  const float* b1 = (const float*)d_in[4];
  const float* gW = (const float*)d_in[5];
  const float* ga = (const float*)d_in[6];
  const float* cW = (const float*)d_in[7];
  const float* cb = (const float*)d_in[8];
  const float* dW = (const float*)d_in[9];
  const float* db = (const float*)d_in[10];
  float* out = (float*)d_out;

  char* base = (char*)d_ws;
  char* w = base;
  auto alloc = [&](size_t bytes) { char* p = w; w += (bytes + 255) & ~(size_t)255; return p; };
  u16 *W0p[3], *W1p[3], *gWp[3], *h1p[3], *hp[3];
  for (int p = 0; p < 3; ++p) W0p[p] = (u16*)alloc((size_t)D_IN * H1_DIM * 2);
  for (int p = 0; p < 3; ++p) W1p[p] = (u16*)alloc((size_t)H1_DIM * H2_DIM * 2);
  for (int p = 0; p < 3; ++p) gWp[p] = (u16*)alloc((size_t)H2_DIM * G_DIM * 2);
  for (int p = 0; p < 3; ++p) h1p[p] = (u16*)alloc((size_t)N_PTS * H1_DIM * 2);
  for (int p = 0; p < 3; ++p) hp[p]  = (u16*)alloc((size_t)N_PTS * H2_DIM * 2);
  float* hF  = (float*)alloc((size_t)N_PTS * H2_DIM * 4);
  float* WhF = (float*)alloc((size_t)N_PTS * G_DIM * 4);
  float* sqv = (float*)alloc(N_PTS * 4);
  float* f1v = (float*)alloc(N_PTS * 4);
  float* f2v = (float*)alloc(N_PTS * 4);
  float* Wc  = (float*)alloc(64 * NOUT * 4);
  float* bc  = (float*)alloc(64 * 4);

  char* pbase = w;
  const size_t MN1 = (size_t)N_PTS * H1_DIM;
  const size_t MN2 = (size_t)N_PTS * H2_DIM;
  const size_t MN3 = (size_t)N_PTS * G_DIM;
  float* P1 = (float*)alloc(4 * MN1 * 4);
  float* P2 = (float*)alloc(4 * MN2 * 4);
  float* P3 = (float*)alloc(4 * MN3 * 4);
  float* Sb = (float*)pbase;

  size_t used_persist = (size_t)(pbase - base);
  size_t avail = (ws_size > used_persist) ? (ws_size - used_persist) / 4 : 0;
  int rowblk = 128;
  const int rcand[] = {6144, 3072, 1536, 768, 384, 256, 128};
  for (int c : rcand) { if ((size_t)c * N_PTS <= avail) { rowblk = c; break; } }

  const int TS = D_IN * H1_DIM + H1_DIM * H2_DIM + H2_DIM * G_DIM;
  trans_split3<<<(TS + 255) / 256, 256, 0, stream>>>(
      W0, W0p[0], W0p[1], W0p[2], W1, W1p[0], W1p[1], W1p[2], gW, gWp[0], gWp[1], gWp[2]);
  prep_head<<<1, 256, 0, stream>>>(cW, cb, dW, db, Wc, bc);

  mfma_gemm<64, true, true, false, false, false, false, false>
      <<<dim3(H1_DIM / 64, N_PTS / 64, 4), 256, 0, stream>>>(
      x, nullptr, nullptr, W0p[0], W0p[1], W0p[2], nullptr,
      P1, nullptr, nullptr, nullptr, D_IN, D_IN / 4, H1_DIM, MN1, 0);
  combine<4, true, true, false, true><<<(int)(MN1 / 1024), 256, 0, stream>>>(
      P1, b0, MN1, H1_DIM, nullptr, h1p[0], h1p[1], h1p[2]);

  mfma_gemm<64, false, true, false, false, false, false, false>
      <<<dim3(H2_DIM / 64, N_PTS / 64, 4), 256, 0, stream>>>(
      h1p[0], h1p[1], h1p[2], W1p[0], W1p[1], W1p[2], nullptr,
      P2, nullptr, nullptr, nullptr, H1_DIM, H1_DIM / 4, H2_DIM, MN2, 0);
  combine<4, true, true, true, true><<<(int)(MN2 / 1024), 256, 0, stream>>>(
      P2, b1, MN2, H2_DIM, hF, hp[0], hp[1], hp[2]);

  mfma_gemm<64, false, true, false, false, false, false, false>
      <<<dim3(G_DIM / 64, N_PTS / 64, 4), 256, 0, stream>>>(
      hp[0], hp[1], hp[2], gWp[0], gWp[1], gWp[2], nullptr,
      P3, nullptr, nullptr, nullptr, H2_DIM, H2_DIM / 4, G_DIM, MN3, 0);
  combine<4, false, false, true, false><<<(int)(MN3 / 1024), 256, 0, stream>>>(
      P3, nullptr, MN3, G_DIM, WhF, nullptr, nullptr, nullptr);

  row_stats<<<N_PTS / 256, 256, 0, stream>>>(hF, WhF, ga, sqv, f1v, f2v);

  // Gram panel(s) writing sortable keys directly, then fused select/att/head
  for (int b = 0; b < N_PTS / rowblk; ++b) {
    mfma_gemm<128, false, false, false, false, false, false, true>
        <<<dim3(N_PTS / 64, rowblk / 128, 1), 256, 0, stream>>>(
        hp[0] + (size_t)b * rowblk * H2_DIM, hp[1] + (size_t)b * rowblk * H2_DIM,
        hp[2] + (size_t)b * rowblk * H2_DIM, hp[0], hp[1], hp[2], sqv,
        Sb, nullptr, nullptr, nullptr, H2_DIM, H2_DIM, N_PTS, 0, b * rowblk);
    topk_att<<<rowblk / 4, 256, 0, stream>>>((const unsigned*)Sb, f1v, f2v, WhF, Wc, bc, out, b * rowblk);
  }
}